// Round 11
// baseline (46.014 us; speedup 1.0000x reference)
//
#include <hip/hip_runtime.h>

// Problem constants (match reference)
#define BATCH 16
#define IMG_H 1024
#define IMG_W 1024
#define WORDS 16                              // 1024 cols / 64 bits
#define TOTAL_PX (BATCH * IMG_H * IMG_W)      // 16777216
#define TOTAL_WORDS (TOTAL_PX / 64)           // 262144 (2 MiB as u64)
typedef unsigned long long u64;
typedef float f32x4 __attribute__((ext_vector_type(4)));

// stable BCE-with-logits: pe = max(x,0) - x*y + log1p(exp(-|x|))
//                            = max(sgn,0) + ln2*log2(1 + 2^(-|x|*log2e)),
// where sgn = (y ? -x : x). Exact for y in {0,1}.
__device__ __forceinline__ float bce1(float x, bool y)
{
    unsigned xu = __float_as_uint(x);
    float sgn = __uint_as_float(xu ^ (y ? 0x80000000u : 0u));
    float a   = __uint_as_float(xu & 0x7fffffffu);
    float t   = __builtin_exp2f(a * -1.44269504088896340736f);
    float l2  = __builtin_log2f(1.0f + t);
    return fmaf(l2, 0.69314718055994530942f, fmaxf(sgn, 0.0f));
}

// ====== kernel A: pipelined dual-stream Σpe (unweighted) + pack bits ======
// Wave owns 2048 contiguous px, 4 iterations of 512 px. 2-deep software
// pipeline: iteration i+1's 10 loads (8 tgt dwords + 2 logit dwordx4) are
// issued (volatile asm - cannot be sunk) before iteration i is consumed
// via counted s_waitcnt. 8 KB/wave in flight during compute.
#define A_NT 256
#define A_WPB (A_NT / 64)                          // 4 waves/block
#define A_BLOCKS (TOTAL_PX / 2048 / A_WPB)         // 2048

// issue one stage: 8 target dwords (stride 256B) + 2 logit dwordx4
#define ISSUE(t, x0, x1, tp, lp)                                   \
    asm volatile(                                                  \
        "global_load_dword %0, %10, off\n\t"                       \
        "global_load_dword %1, %10, off offset:256\n\t"            \
        "global_load_dword %2, %10, off offset:512\n\t"            \
        "global_load_dword %3, %10, off offset:768\n\t"            \
        "global_load_dword %4, %10, off offset:1024\n\t"           \
        "global_load_dword %5, %10, off offset:1280\n\t"           \
        "global_load_dword %6, %10, off offset:1536\n\t"           \
        "global_load_dword %7, %10, off offset:1792\n\t"           \
        "global_load_dwordx4 %8, %11, off\n\t"                     \
        "global_load_dwordx4 %9, %11, off offset:1024"             \
        : "=&v"(t[0]), "=&v"(t[1]), "=&v"(t[2]), "=&v"(t[3]),      \
          "=&v"(t[4]), "=&v"(t[5]), "=&v"(t[6]), "=&v"(t[7]),      \
          "=&v"(x0), "=&v"(x1)                                     \
        : "v"(tp), "v"(lp))

#define WAIT_T(n, t)                                               \
    asm volatile("s_waitcnt vmcnt(" #n ")"                         \
        : "+v"(t[0]), "+v"(t[1]), "+v"(t[2]), "+v"(t[3]),          \
          "+v"(t[4]), "+v"(t[5]), "+v"(t[6]), "+v"(t[7]))

#define WAIT_X(n, x0, x1)                                          \
    asm volatile("s_waitcnt vmcnt(" #n ")" : "+v"(x0), "+v"(x1))

__global__ __launch_bounds__(A_NT, 5)
void wbce_main_kernel(const float* __restrict__ logits,
                      const float* __restrict__ targets,
                      u64* __restrict__ pak,
                      float* __restrict__ partial)
{
    __shared__ float sRed[A_WPB];
    const int tid = threadIdx.x, lane = tid & 63, wv = tid >> 6;
    const int gw = blockIdx.x * A_WPB + wv;        // wave id [0, 8192)
    const size_t basePx = (size_t)gw * 2048;
    const float* tp0 = targets + basePx + lane;        // dword stream base
    const float* lp0 = logits  + basePx + lane * 4;    // dwordx4 stream base

    float tA[8], tB[8];
    f32x4 xA0, xA1, xB0, xB1;
    float acc = 0.0f;

    // consume one stage: ballots -> 8 packed words; y-bit select; 8x bce
    #define STAGE_CONSUME(t, x0, x1, it)                                     \
    do {                                                                     \
        u64 b0 = __ballot(t[0] > 0.5f), b1 = __ballot(t[1] > 0.5f);          \
        u64 b2 = __ballot(t[2] > 0.5f), b3 = __ballot(t[3] > 0.5f);          \
        u64 b4 = __ballot(t[4] > 0.5f), b5 = __ballot(t[5] > 0.5f);          \
        u64 b6 = __ballot(t[6] > 0.5f), b7 = __ballot(t[7] > 0.5f);          \
        /* y-bits for this lane's 8 logits: px 4*lane+e (word lane>>4) */    \
        u64 w0 = (lane & 32) ? ((lane & 16) ? b3 : b2)                       \
                             : ((lane & 16) ? b1 : b0);                      \
        u64 w1 = (lane & 32) ? ((lane & 16) ? b7 : b6)                       \
                             : ((lane & 16) ? b5 : b4);                      \
        const unsigned sh = (lane & 15) * 4u;                                \
        unsigned yb0 = (unsigned)(w0 >> sh) & 0xFu;                          \
        unsigned yb1 = (unsigned)(w1 >> sh) & 0xFu;                          \
        acc += bce1(x0.x, yb0 & 1u) + bce1(x0.y, yb0 & 2u)                   \
             + bce1(x0.z, yb0 & 4u) + bce1(x0.w, yb0 & 8u)                   \
             + bce1(x1.x, yb1 & 1u) + bce1(x1.y, yb1 & 2u)                   \
             + bce1(x1.z, yb1 & 4u) + bce1(x1.w, yb1 & 8u);                  \
        if (lane == 0) {                                                     \
            ulonglong2* q = (ulonglong2*)(pak + (size_t)gw * 32 + (it) * 8); \
            q[0] = make_ulonglong2(b0, b1);                                  \
            q[1] = make_ulonglong2(b2, b3);                                  \
            q[2] = make_ulonglong2(b4, b5);                                  \
            q[3] = make_ulonglong2(b6, b7);                                  \
        }                                                                    \
    } while (0)

    ISSUE(tA, xA0, xA1, tp0,        lp0);            // stage 0 in flight
    ISSUE(tB, xB0, xB1, tp0 + 512,  lp0 + 512);      // stage 1 in flight (20 out)

    // iter 0 (stage A); issue iter 2 into A after consuming? No - consume A,
    // then refill A with iter 2. Counted waits: stores assumed retired.
    WAIT_T(12, tA);                                  // A tgt done (B's 10 + A x4 out)
    WAIT_X(10, xA0, xA1);                            // A logits done
    STAGE_CONSUME(tA, xA0, xA1, 0);
    ISSUE(tA, xA0, xA1, tp0 + 1024, lp0 + 1024);     // stage 2 (20 out)

    // iter 1 (stage B)
    WAIT_T(12, tB);
    WAIT_X(10, xB0, xB1);
    STAGE_CONSUME(tB, xB0, xB1, 1);
    ISSUE(tB, xB0, xB1, tp0 + 1536, lp0 + 1536);     // stage 3 (20 out)

    // iter 2 (stage A)
    WAIT_T(12, tA);
    WAIT_X(10, xA0, xA1);
    STAGE_CONSUME(tA, xA0, xA1, 2);

    // iter 3 (stage B) - last, drain
    WAIT_T(2, tB);
    WAIT_X(0, xB0, xB1);
    STAGE_CONSUME(tB, xB0, xB1, 3);

    // wave64 shuffle tree, cross-wave via LDS, one partial per block
    #pragma unroll
    for (int off = 32; off > 0; off >>= 1)
        acc += __shfl_down(acc, off, 64);
    if (lane == 0) sRed[wv] = acc;
    __syncthreads();
    if (tid == 0) {
        float s = 0.0f;
        #pragma unroll
        for (int i = 0; i < A_WPB; ++i) s += sRed[i];
        partial[blockIdx.x] = s;
    }
}

// ====== kernel B: bit-morphology + wave-collective boundary correction ======
#define B_NT 256
__global__ __launch_bounds__(B_NT, 8)
void wbce_morph_kernel(const float* __restrict__ logits,
                       const u64* __restrict__ pak,
                       float* __restrict__ partial2)
{
    __shared__ float sRed[B_NT / 64];
    const int tid = threadIdx.x, lane = tid & 63, wv = tid >> 6;
    const int idx = blockIdx.x * B_NT + tid;       // word id [0, 262144)
    const int w   = idx & 15;
    const int row = (idx >> 4) & (IMG_H - 1);
    const int img = idx >> 14;
    const u64* ib = pak + (size_t)img * (IMG_H * WORDS);

    u64 d = 0ULL, e = ~0ULL, Cw = 0ULL;
    const int r0 = row >= 4 ? row - 4 : 0;             // OOB rows: neutral
    const int r1 = row <= IMG_H - 5 ? row + 4 : IMG_H - 1;
    for (int r = r0; r <= r1; ++r) {
        const u64* rp = ib + (size_t)r * WORDS;
        u64 c  = rp[w];
        u64 P  = (w > 0)  ? rp[w - 1] : 0ULL;          // OOB col: dilate fill 0
        u64 N  = (w < 15) ? rp[w + 1] : 0ULL;
        u64 Pe = (w > 0)  ? P : ~0ULL;                 // OOB col: erode fill 1
        u64 Ne = (w < 15) ? N : ~0ULL;
        u64 hd = c, he = c;
        #pragma unroll
        for (int s = 1; s <= 4; ++s) {
            hd |= (c >> s) | (N  << (64 - s));
            hd |= (c << s) | (P  >> (64 - s));
            he &= (c >> s) | (Ne << (64 - s));
            he &= (c << s) | (Pe >> (64 - s));
        }
        d |= hd;
        e &= he;
        if (r == row) Cw = c;
    }
    u64 bnd = d & ~e;                                  // boundary bits

    // wave-collective sparse correction: weight 3 = 1 (in A) + 2 (here)
    float acc = 0.0f;
    u64 act_mask = __ballot(bnd != 0ULL);              // wave-uniform
    const int wavebase = blockIdx.x * B_NT + wv * 64;  // word id of lane 0
    while (act_mask) {
        int s = __builtin_ctzll(act_mask);
        act_mask &= act_mask - 1;
        u64 bs = __shfl(bnd, s, 64);
        u64 cs = __shfl(Cw,  s, 64);
        if ((bs >> lane) & 1ULL) {
            float x = logits[((size_t)(wavebase + s) << 6) + lane];
            acc += 2.0f * bce1(x, ((cs >> lane) & 1ULL) != 0ULL);
        }
    }

    #pragma unroll
    for (int off = 32; off > 0; off >>= 1)
        acc += __shfl_down(acc, off, 64);
    if (lane == 0) sRed[wv] = acc;
    __syncthreads();
    if (tid == 0) {
        float s = 0.0f;
        #pragma unroll
        for (int i = 0; i < B_NT / 64; ++i) s += sRed[i];
        partial2[blockIdx.x] = s;
    }
}

// ====== kernel C: final reduce of 2048 + 1024 partials -> mean ======
#define D_NT 1024
__global__ __launch_bounds__(D_NT, 1)
void wbce_final_kernel(const float* __restrict__ partial,    // 2048 floats
                       const float* __restrict__ partial2,   // 1024 floats
                       float* __restrict__ out)
{
    __shared__ float sRed[D_NT / 64];
    const int tid = threadIdx.x;
    float acc = partial2[tid];
    if (tid < 512) {
        float4 a = ((const float4*)partial)[tid];      // 512 float4 = 2048
        acc += (a.x + a.y) + (a.z + a.w);
    }
    #pragma unroll
    for (int off = 32; off > 0; off >>= 1)
        acc += __shfl_down(acc, off, 64);
    if ((tid & 63) == 0) sRed[tid >> 6] = acc;
    __syncthreads();
    if (tid == 0) {
        float s = 0.0f;
        #pragma unroll
        for (int i = 0; i < D_NT / 64; ++i) s += sRed[i];
        out[0] = s * (1.0f / 16777216.0f);             // mean: 1/2^24 exact
    }
}

extern "C" void kernel_launch(void* const* d_in, const int* in_sizes, int n_in,
                              void* d_out, int out_size, void* d_ws, size_t ws_size,
                              hipStream_t stream) {
    const float* logits  = (const float*)d_in[0];
    const float* targets = (const float*)d_in[1];
    float* out = (float*)d_out;

    // scratch: pak 2 MiB | partial 8 KiB | partial2 4 KiB
    char* ws = (char*)d_ws;
    u64*   pak      = (u64*)ws;
    float* partial  = (float*)(ws + (2u << 20));
    float* partial2 = (float*)(ws + (2u << 20) + 8192);

    // A) both 67MB streams, 2-deep asm pipeline: Σpe (unweighted) + pack
    wbce_main_kernel<<<dim3(A_BLOCKS), dim3(A_NT), 0, stream>>>(
        logits, targets, pak, partial);

    // B) word-level 9x9 bit-morphology + sparse boundary correction
    wbce_morph_kernel<<<dim3(TOTAL_WORDS / B_NT), dim3(B_NT), 0, stream>>>(
        logits, pak, partial2);

    // C) final reduce -> out[0]
    wbce_final_kernel<<<dim3(1), dim3(D_NT), 0, stream>>>(partial, partial2, out);
}

// Round 12
// 41.045 us; speedup vs baseline: 1.1211x; 1.1211x over previous
//
#include <hip/hip_runtime.h>

// Problem constants (match reference)
#define BATCH 16
#define IMG_H 1024
#define IMG_W 1024
#define WORDS 16            // 1024 cols / 64 bits
#define TY 32               // output rows per block
#define SROWS (TY + 8)      // 40 staged rows (+-4 halo)
#define NT 512              // 8 waves
#define NWAVES (NT / 64)

typedef unsigned long long u64;
typedef float f32x4 __attribute__((ext_vector_type(4)));

__global__ void wbce_zero_kernel(float* out) { out[0] = 0.0f; }

// Fused kernel, structure identical to the proven 37.5us version, plus an
// inline-asm logits prefetch: batch1 (8 x dwordx4/thread = 128B) issued at
// kernel ENTRY so the logit stream flies concurrently with target staging
// and bit-morphology; batch2 issued after the last barrier. Volatile asm
// cannot be sunk by the compiler (the failure mode of round 2).
__global__ __launch_bounds__(NT, 4)
void wbce_kernel(const float* __restrict__ logits,
                 const float* __restrict__ targets,
                 float* __restrict__ out)
{
    __shared__ u64 sT [SROWS * WORDS];   // packed targets (halo rows)
    __shared__ u64 sHD[SROWS * WORDS];   // horizontal 9-dilate
    __shared__ u64 sHE[SROWS * WORDS];   // horizontal 9-erode
    __shared__ u64 sBnd[TY * WORDS];     // boundary bits
    __shared__ float sRed[NWAVES];

    const int tid  = threadIdx.x;
    const int lane = tid & 63;
    const int wv   = tid >> 6;
    const int rowBase = blockIdx.x * TY;
    const int b = blockIdx.y;

    const float* tgt = targets + (size_t)b * (IMG_H * IMG_W);
    const float* lg  = logits  + (size_t)b * (IMG_H * IMG_W);

    // ---- logits prefetch, batch 1: wave wv owns rows [rowBase+4wv, +4);
    // lane's float4 m (m=0..15) at byte offset m*1024 from its base.
    const float* a0 = lg + (size_t)rowBase * IMG_W + (wv << 12) + (lane << 2);
    const float* a1 = a0 + 1024;         // m = 4..7
    f32x4 p0, p1, p2, p3, p4, p5, p6, p7;
    asm volatile(
        "global_load_dwordx4 %0, %8, off\n\t"
        "global_load_dwordx4 %1, %8, off offset:1024\n\t"
        "global_load_dwordx4 %2, %8, off offset:2048\n\t"
        "global_load_dwordx4 %3, %8, off offset:3072\n\t"
        "global_load_dwordx4 %4, %9, off\n\t"
        "global_load_dwordx4 %5, %9, off offset:1024\n\t"
        "global_load_dwordx4 %6, %9, off offset:2048\n\t"
        "global_load_dwordx4 %7, %9, off offset:3072"
        : "=&v"(p0), "=&v"(p1), "=&v"(p2), "=&v"(p3),
          "=&v"(p4), "=&v"(p5), "=&v"(p6), "=&v"(p7)
        : "v"(a0), "v"(a1));

    // ---- Phase A: ballot-pack targets, 4 words (1KB) per wave-iter ----
    for (int it4 = wv * 4; it4 < SROWS * WORDS; it4 += NWAVES * 4) {
        int sr = it4 >> 4;              // (it4&15) in {0,4,8,12}: no row straddle
        int gr = rowBase + sr - 4;
        float v0 = 0.f, v1 = 0.f, v2 = 0.f, v3 = 0.f;
        if (gr >= 0 && gr < IMG_H) {    // wave-uniform branch
            const float* rp = tgt + (size_t)gr * IMG_W + ((it4 & 15) * 64) + lane;
            v0 = rp[0]; v1 = rp[64]; v2 = rp[128]; v3 = rp[192];
        }
        u64 m0 = __ballot(v0 > 0.5f);
        u64 m1 = __ballot(v1 > 0.5f);
        u64 m2 = __ballot(v2 > 0.5f);
        u64 m3 = __ballot(v3 > 0.5f);
        if (lane == 0) {
            sT[it4]     = m0; sT[it4 + 1] = m1;
            sT[it4 + 2] = m2; sT[it4 + 3] = m3;
        }
    }
    __syncthreads();   // barrier drain also retires batch1 (arrived during A)

    // ---- Phase B: horizontal +-4 bitwise OR/AND (640 words, 2 iters) ----
    for (int it = tid; it < SROWS * WORDS; it += NT) {
        int sr = it >> 4;
        int w  = it & 15;
        int gr = rowBase + sr - 4;
        u64 hd = 0ULL, he = ~0ULL;      // OOB row: neutral for vertical pass
        if (gr >= 0 && gr < IMG_H) {
            u64 C  = sT[it];
            u64 P  = (w > 0)  ? sT[it - 1] : 0ULL;   // OOB col: dilate fill 0
            u64 N  = (w < 15) ? sT[it + 1] : 0ULL;
            u64 Pe = (w > 0)  ? P : ~0ULL;           // OOB col: erode fill 1
            u64 Ne = (w < 15) ? N : ~0ULL;
            u64 d = C, e = C;
            #pragma unroll
            for (int s = 1; s <= 4; ++s) {
                d |= (C >> s) | (N  << (64 - s));
                d |= (C << s) | (P  >> (64 - s));
                e &= (C >> s) | (Ne << (64 - s));
                e &= (C << s) | (Pe >> (64 - s));
            }
            hd = d; he = e;
        }
        sHD[it] = hd;
        sHE[it] = he;
    }
    __syncthreads();

    // ---- Phase B2: vertical 9-row OR/AND (512 words = 1/thread) ----
    {
        int r = tid >> 4, w = tid & 15;
        u64 d = 0ULL, e = ~0ULL;
        #pragma unroll
        for (int k = 0; k < 9; ++k) {
            d |= sHD[(r + k) * WORDS + w];
            e &= sHE[(r + k) * WORDS + w];
        }
        sBnd[tid] = d & ~e;
    }
    __syncthreads();

    // ---- logits prefetch, batch 2 (m = 8..15) ----
    const float* a2 = a0 + 2048;
    const float* a3 = a0 + 3072;
    f32x4 q0, q1, q2, q3, q4, q5, q6, q7;
    asm volatile(
        "global_load_dwordx4 %0, %8, off\n\t"
        "global_load_dwordx4 %1, %8, off offset:1024\n\t"
        "global_load_dwordx4 %2, %8, off offset:2048\n\t"
        "global_load_dwordx4 %3, %8, off offset:3072\n\t"
        "global_load_dwordx4 %4, %9, off\n\t"
        "global_load_dwordx4 %5, %9, off offset:1024\n\t"
        "global_load_dwordx4 %6, %9, off offset:2048\n\t"
        "global_load_dwordx4 %7, %9, off offset:3072"
        : "=&v"(q0), "=&v"(q1), "=&v"(q2), "=&v"(q3),
          "=&v"(q4), "=&v"(q5), "=&v"(q6), "=&v"(q7)
        : "v"(a2), "v"(a3));

    // ---- Phase C: fused BCE from register logits + LDS bit-words ----
    const unsigned* sBnd32 = (const unsigned*)sBnd;
    const unsigned* sT32   = (const unsigned*)sT;
    float acc = 0.0f;

    #define CONSUME(x4, m)                                                    \
    do {                                                                      \
        int idx = (m) * 64 + lane;          /* [0,1024) within wave span */   \
        int r   = (wv << 2) + (idx >> 8);   /* tile row [0,32) */             \
        int pos = idx & 255;                /* float4 within row */           \
        int wi  = r * WORDS + (pos >> 4);                                     \
        int hf  = (pos >> 3) & 1;                                             \
        int sh  = (pos & 7) * 4;                                              \
        unsigned bbw = sBnd32[wi * 2 + hf];                                   \
        unsigned tbw = sT32[(wi + 4 * WORDS) * 2 + hf];  /* row r+4 */        \
        const float xs[4] = {x4.x, x4.y, x4.z, x4.w};                         \
        _Pragma("unroll")                                                     \
        for (int jj = 0; jj < 4; ++jj) {                                      \
            unsigned tb = (tbw >> (sh + jj)) & 1u;                            \
            unsigned bb = (bbw >> (sh + jj)) & 1u;                            \
            unsigned xu = __float_as_uint(xs[jj]);                            \
            float sgn = __uint_as_float(xu ^ (tb << 31));                     \
            float av  = __uint_as_float(xu & 0x7fffffffu);                    \
            float t   = __builtin_exp2f(av * -1.44269504088896340736f);       \
            float l2  = __builtin_log2f(1.0f + t);                            \
            float pe  = fmaf(l2, 0.69314718055994530942f, fmaxf(sgn, 0.0f));  \
            float wg  = fmaf((float)bb, 2.0f, 1.0f);   /* BOUNDARY_WEIGHT=3 */\
            acc = fmaf(wg, pe, acc);                                          \
        }                                                                     \
    } while (0)

    // batch1 already resident (drained at the phase-A barrier): no wait
    CONSUME(p0, 0); CONSUME(p1, 1); CONSUME(p2, 2); CONSUME(p3, 3);
    CONSUME(p4, 4); CONSUME(p5, 5); CONSUME(p6, 6); CONSUME(p7, 7);

    // batch2: single drain, then consume
    asm volatile("s_waitcnt vmcnt(0)"
        : "+v"(q0), "+v"(q1), "+v"(q2), "+v"(q3),
          "+v"(q4), "+v"(q5), "+v"(q6), "+v"(q7));
    CONSUME(q0, 8);  CONSUME(q1, 9);  CONSUME(q2, 10); CONSUME(q3, 11);
    CONSUME(q4, 12); CONSUME(q5, 13); CONSUME(q6, 14); CONSUME(q7, 15);
    #undef CONSUME

    // ---- block reduction: wave64 shuffle tree, cross-wave via LDS ----
    #pragma unroll
    for (int off = 32; off > 0; off >>= 1)
        acc += __shfl_down(acc, off, 64);
    if (lane == 0) sRed[wv] = acc;
    __syncthreads();
    if (tid == 0) {
        float s = 0.0f;
        #pragma unroll
        for (int i = 0; i < NWAVES; ++i) s += sRed[i];
        atomicAdd(out, s * (1.0f / 16777216.0f));   // mean: 1/2^24 exact
    }
}

extern "C" void kernel_launch(void* const* d_in, const int* in_sizes, int n_in,
                              void* d_out, int out_size, void* d_ws, size_t ws_size,
                              hipStream_t stream) {
    const float* logits  = (const float*)d_in[0];
    const float* targets = (const float*)d_in[1];
    float* out = (float*)d_out;

    // d_out is poisoned before timing and not re-poisoned between replays:
    // zero it every call (graph-capturable kernel, same stream).
    wbce_zero_kernel<<<dim3(1), dim3(1), 0, stream>>>(out);

    dim3 grid(IMG_H / TY, BATCH);   // 32 x 16 = 512 blocks, 8 waves each
    dim3 block(NT);
    wbce_kernel<<<grid, block, 0, stream>>>(logits, targets, out);
}